// Round 2
// baseline (190.262 us; speedup 1.0000x reference)
//
#include <hip/hip_runtime.h>
#include <hip/hip_bf16.h>

typedef __attribute__((ext_vector_type(8))) short short8;
typedef __attribute__((ext_vector_type(4))) float float4v;
typedef __attribute__((ext_vector_type(2))) float float2v;

#define S_A 0.04419417382415922f   // 1/(16*sqrt(2)) : a2, and a1*s2
#define S_B 0.025515518153991442f  // 1/(16*sqrt(6)) : a2/sqrt(3), and a1/sqrt(6)
#define S_C 0.0625f                // 1/16 : a1

// Pack two fp32 -> two bf16 (RNE) in one dword: low = a, high = b.
static __device__ __forceinline__ unsigned pkbf(float a, float b) {
#if __has_builtin(__builtin_amdgcn_cvt_pk_bf16_f32)
    auto v = __builtin_amdgcn_cvt_pk_bf16_f32(a, b);   // v_cvt_pk_bf16_f32 (gfx950)
    return __builtin_bit_cast(unsigned, v);
#else
    unsigned ua = __builtin_bit_cast(unsigned, a);
    unsigned ub = __builtin_bit_cast(unsigned, b);
    ua += 0x7fffu + ((ua >> 16) & 1u);                 // RNE
    ub += 0x7fffu + ((ub >> 16) & 1u);
    return __builtin_amdgcn_perm(ub, ua, 0x07060302);  // {hi16(ub), hi16(ua)}
#endif
}

// ---- Prep: W (5 x 16^3 fp32) -> bf16 in MFMA B-fragment layout in d_ws ----
// Fragment addr for path p, chunk c (k=c*32+kk), lane, j:
//   lane = (kk>>3)*16 + w, j = kk&7 ; out[((c*5+p)*64 + lane)*8 + j]
// so the main kernel's per-(c,p) load is 64 lanes x 16B contiguous = 1KB coalesced.
__global__ void wprep_kernel(const float* __restrict__ wA, const float* __restrict__ wB,
                             const float* __restrict__ wC, const float* __restrict__ wD,
                             const float* __restrict__ wE, unsigned short* __restrict__ wout)
{
    int e = blockIdx.x * 256 + threadIdx.x;
    if (e >= 5 * 4096) return;
    int p = e >> 12;
    int rem = e & 4095;                    // rem = k*16 + w
    const float* wp = (p == 0) ? wA : (p == 1) ? wB : (p == 2) ? wC : (p == 3) ? wD : wE;
    unsigned u = __builtin_bit_cast(unsigned, wp[rem]);
    u += 0x7fffu + ((u >> 16) & 1u);       // RNE to bf16
    int k = rem >> 4, w = rem & 15;
    int c = k >> 5, kk = k & 31;
    int lane = ((kk >> 3) << 4) | w;
    int j = kk & 7;
    wout[(((c * 5 + p) * 64 + lane) << 3) | j] = (unsigned short)(u >> 16);
}

// One wave = one z-tile of 16 rows. Block = 4 waves = 64 rows.
// GEMM per m-slot: out_m[z(16), w(16)] += A_m[z,k] * W_m[k,w], K=256 (uv), 8 chunks of 32.
// A-frag: lane l holds A[row=l&15][k = c*32 + (l>>4)*8 + j]
// B-frag: lane l holds W[k][w=l&15]
// C/D:    lane l, reg r -> D[row=(l>>4)*4+r][col=l&15]
__global__ __launch_bounds__(256, 4)
void tsq_kernel(const float* __restrict__ x,
                const unsigned short* __restrict__ wfrag,
                float* __restrict__ out,
                int nrows)
{
    // x tile: 64 rows x 64 floats, stride 68 (16B-aligned rows; 8-apart rows share a
    // bank -> only 2-way aliasing, which is free on gfx950)
    __shared__ __attribute__((aligned(16))) float xlds[64 * 68];

    const int tid = threadIdx.x;

    // ---- stage x tile (coalesced float4) ----
    {
        const long long rowbase = (long long)blockIdx.x * 64;
        const float* xg = x + rowbase * 64;
        #pragma unroll
        for (int q = 0; q < 4; q++) {
            int f = q * 1024 + tid * 4;
            int row = f >> 6, col = f & 63;
            float4v v = {0.f, 0.f, 0.f, 0.f};
            if (rowbase + row < nrows) v = *(const float4v*)(xg + f);
            *(float4v*)&xlds[row * 68 + col] = v;
        }
    }
    __syncthreads();

    const int wave = tid >> 6;
    const int l = tid & 63;
    const long long z0 = (long long)blockIdx.x * 64 + wave * 16;
    if (z0 >= nrows) return;   // nrows % 16 == 0, so live waves are full tiles

    const int r  = l & 15;        // my A-row (z-local); also my w-col for output
    const int g  = l >> 4;        // quad
    const int v0 = (g & 1) * 8;   // my v-range base (fixed across chunks)
    const int uo = g >> 1;        // u = c*2 + uo
    const float* xr = &xlds[(wave * 16 + r) * 68];

    // v-side x cached in registers as float2 pairs (cells 2t, 2t+1)
    float2v A0v[4], Xv[4], Yv[4], Zv[4];
    {
        float a[8], b[24];
        #pragma unroll
        for (int q = 0; q < 2; q++) *(float4v*)&a[q * 4] = *(const float4v*)(xr + v0 + q * 4);
        #pragma unroll
        for (int q = 0; q < 6; q++) *(float4v*)&b[q * 4] = *(const float4v*)(xr + 16 + v0 * 3 + q * 4);
        #pragma unroll
        for (int t = 0; t < 4; t++) {
            A0v[t] = (float2v){a[2 * t], a[2 * t + 1]};
            Xv[t]  = (float2v){b[6 * t + 0], b[6 * t + 3]};
            Yv[t]  = (float2v){b[6 * t + 1], b[6 * t + 4]};
            Zv[t]  = (float2v){b[6 * t + 2], b[6 * t + 5]};
        }
    }

    float4v acc[13];
    #pragma unroll
    for (int m = 0; m < 13; m++) acc[m] = (float4v){0.f, 0.f, 0.f, 0.f};

    // m-slot -> path: 0:w0  1:w2  2-4:w1  5-7:w3  8-12:w4
    constexpr int pm[13] = {0, 1, 2, 2, 2, 3, 3, 3, 4, 4, 4, 4, 4};

    const short8* wbase = (const short8*)wfrag;

    #pragma unroll
    for (int c = 0; c < 8; c++) {
        // W B-fragments for this chunk (L2-resident, fully coalesced)
        short8 wf[5];
        #pragma unroll
        for (int p = 0; p < 5; p++) wf[p] = wbase[(c * 5 + p) * 64 + l];

        const int u = c * 2 + uo;
        const float u0 = xr[u];
        const float ux = xr[16 + u * 3 + 0];
        const float uy = xr[16 + u * 3 + 1];
        const float uz = xr[16 + u * 3 + 2];

        unsigned fri[13][4];
        #pragma unroll
        for (int t = 0; t < 4; t++) {
            const float2v X = Xv[t], Y = Yv[t], Z = Zv[t];
            const float2v p00 = ux * X, p01 = ux * Y, p02 = ux * Z;
            const float2v p10 = uy * X, p11 = uy * Y, p12 = uy * Z;
            const float2v p20 = uz * X, p21 = uz * Y, p22 = uz * Z;
            float2v bv[13];
            bv[0]  = u0 * A0v[t];                 // 0e x 0e
            bv[1]  = p00 + p11 + p22;             // dot      (1/sqrt3 in epilogue)
            bv[2]  = u0 * X;                      // 0e x 1o
            bv[3]  = u0 * Y;
            bv[4]  = u0 * Z;
            bv[5]  = p12 - p21;                   // cross    (s2 in epilogue)
            bv[6]  = p20 - p02;
            bv[7]  = p01 - p10;
            bv[8]  = p01 + p10;                   // 2e: xy
            bv[9]  = p12 + p21;                   //     yz
            bv[10] = 2.0f * p22 - p00 - p11;      //     3z^2-r^2 (1/sqrt6)
            bv[11] = p02 + p20;                   //     xz
            bv[12] = p00 - p11;                   //     x^2-y^2  (s2)
            #pragma unroll
            for (int m = 0; m < 13; m++) fri[m][t] = pkbf(bv[m].x, bv[m].y);
        }

        #pragma unroll
        for (int m = 0; m < 13; m++) {
            short8 frm = __builtin_bit_cast(short8, *(unsigned __attribute__((ext_vector_type(4)))*)fri[m]);
            acc[m] = __builtin_amdgcn_mfma_f32_16x16x32_bf16(frm, wf[pm[m]], acc[m], 0, 0, 0);
        }
    }

    // ---- Epilogue: scale + store. lane: w = l&15, rows z0 + g*4 + reg ----
    const int w = r;
    float* outp = out + (z0 + g * 4) * 192;
    #pragma unroll
    for (int reg = 0; reg < 4; reg++) {
        float* rowp = outp + reg * 192;
        rowp[w] = S_A * acc[0][reg] + S_B * acc[1][reg];      // 0e (two paths)
        rowp[16 + w * 3 + 0]  = S_C * acc[2][reg];            // 1o
        rowp[16 + w * 3 + 1]  = S_C * acc[3][reg];
        rowp[16 + w * 3 + 2]  = S_C * acc[4][reg];
        rowp[64 + w * 3 + 0]  = S_A * acc[5][reg];            // 1e
        rowp[64 + w * 3 + 1]  = S_A * acc[6][reg];
        rowp[64 + w * 3 + 2]  = S_A * acc[7][reg];
        rowp[112 + w * 5 + 0] = S_A * acc[8][reg];            // 2e
        rowp[112 + w * 5 + 1] = S_A * acc[9][reg];
        rowp[112 + w * 5 + 2] = S_B * acc[10][reg];
        rowp[112 + w * 5 + 3] = S_A * acc[11][reg];
        rowp[112 + w * 5 + 4] = S_A * acc[12][reg];
    }
}

extern "C" void kernel_launch(void* const* d_in, const int* in_sizes, int n_in,
                              void* d_out, int out_size, void* d_ws, size_t ws_size,
                              hipStream_t stream) {
    const float* x  = (const float*)d_in[0];
    const float* w0 = (const float*)d_in[1];
    const float* w1 = (const float*)d_in[2];
    const float* w2 = (const float*)d_in[3];
    const float* w3 = (const float*)d_in[4];
    const float* w4 = (const float*)d_in[5];
    float* out = (float*)d_out;
    unsigned short* wfrag = (unsigned short*)d_ws;   // 40 KB used
    (void)ws_size; (void)n_in; (void)out_size;

    const int nrows = in_sizes[0] / 64;              // 100000
    const int nblocks = (nrows + 63) / 64;           // 1563

    // path order: {w0, w2, w1, w3, w4}
    wprep_kernel<<<dim3(80), dim3(256), 0, stream>>>(w0, w2, w1, w3, w4, wfrag);
    tsq_kernel<<<dim3(nblocks), dim3(256), 0, stream>>>(x, wfrag, out, nrows);
}

// Round 3
// 139.618 us; speedup vs baseline: 1.3627x; 1.3627x over previous
//
#include <hip/hip_runtime.h>
#include <hip/hip_bf16.h>

typedef __attribute__((ext_vector_type(8))) short short8;
typedef __attribute__((ext_vector_type(4))) float float4v;
typedef __attribute__((ext_vector_type(2))) float float2v;

#define S_A 0.04419417382415922f   // 1/(16*sqrt(2)) : a2, and a1*s2
#define S_B 0.025515518153991442f  // 1/(16*sqrt(6)) : a2/sqrt(3), and a1/sqrt(6)
#define S_C 0.0625f                // 1/16 : a1

// Pack two fp32 -> two bf16 (RNE) in one dword: low = a, high = b.
static __device__ __forceinline__ unsigned pkbf(float a, float b) {
#if __has_builtin(__builtin_amdgcn_cvt_pk_bf16_f32)
    auto v = __builtin_amdgcn_cvt_pk_bf16_f32(a, b);   // v_cvt_pk_bf16_f32 (gfx950)
    return __builtin_bit_cast(unsigned, v);
#else
    unsigned ua = __builtin_bit_cast(unsigned, a);
    unsigned ub = __builtin_bit_cast(unsigned, b);
    ua += 0x7fffu + ((ua >> 16) & 1u);                 // RNE
    ub += 0x7fffu + ((ub >> 16) & 1u);
    return __builtin_amdgcn_perm(ub, ua, 0x07060302);  // {hi16(ub), hi16(ua)}
#endif
}

// ---- Prep: W (5 x 16^3 fp32) -> bf16 in MFMA B-fragment layout in d_ws ----
// Fragment addr for path p, chunk c (k=c*32+kk), lane, j:
//   lane = (kk>>3)*16 + w, j = kk&7 ; out[((c*5+p)*64 + lane)*8 + j]
// so the main kernel's per-(c,p) load is 64 lanes x 16B contiguous = 1KB coalesced.
__global__ void wprep_kernel(const float* __restrict__ wA, const float* __restrict__ wB,
                             const float* __restrict__ wC, const float* __restrict__ wD,
                             const float* __restrict__ wE, unsigned short* __restrict__ wout)
{
    int e = blockIdx.x * 256 + threadIdx.x;
    if (e >= 5 * 4096) return;
    int p = e >> 12;
    int rem = e & 4095;                    // rem = k*16 + w
    const float* wp = (p == 0) ? wA : (p == 1) ? wB : (p == 2) ? wC : (p == 3) ? wD : wE;
    unsigned u = __builtin_bit_cast(unsigned, wp[rem]);
    u += 0x7fffu + ((u >> 16) & 1u);       // RNE to bf16
    int k = rem >> 4, w = rem & 15;
    int c = k >> 5, kk = k & 31;
    int lane = ((kk >> 3) << 4) | w;
    int j = kk & 7;
    wout[(((c * 5 + p) * 64 + lane) << 3) | j] = (unsigned short)(u >> 16);
}

// One wave = one z-tile of 16 rows. Block = 4 waves = 64 rows.
// GEMM per m-slot: out_m[z(16), w(16)] += A_m[z,k] * W_m[k,w], K=256 (uv), 8 chunks of 32.
// A-frag: lane l holds A[row=l&15][k = c*32 + (l>>4)*8 + j]
// B-frag: lane l holds W[k][w=l&15]
// C/D:    lane l, reg r -> D[row=(l>>4)*4+r][col=l&15]
//
// launch_bounds(256,2): peak live regs ~190 (acc 52 + fri 52 + vcache 32 + wf 20 +
// products 18 + addr). Cap 128 (=256,4) spilled ~300MB to scratch (round 2);
// cap 256 must not spill.
__global__ __launch_bounds__(256, 2)
void tsq_kernel(const float* __restrict__ x,
                const unsigned short* __restrict__ wfrag,
                float* __restrict__ out,
                int nrows)
{
    // x tile: 64 rows x 64 floats, stride 68 (16B-aligned rows; 8-apart rows share a
    // bank -> only 2-way aliasing, which is free on gfx950)
    __shared__ __attribute__((aligned(16))) float xlds[64 * 68];

    const int tid = threadIdx.x;

    // ---- stage x tile (coalesced float4) ----
    {
        const long long rowbase = (long long)blockIdx.x * 64;
        const float* xg = x + rowbase * 64;
        #pragma unroll
        for (int q = 0; q < 4; q++) {
            int f = q * 1024 + tid * 4;
            int row = f >> 6, col = f & 63;
            float4v v = {0.f, 0.f, 0.f, 0.f};
            if (rowbase + row < nrows) v = *(const float4v*)(xg + f);
            *(float4v*)&xlds[row * 68 + col] = v;
        }
    }
    __syncthreads();

    const int wave = tid >> 6;
    const int l = tid & 63;
    const long long z0 = (long long)blockIdx.x * 64 + wave * 16;
    if (z0 >= nrows) return;   // nrows % 16 == 0, so live waves are full tiles

    const int r  = l & 15;        // my A-row (z-local); also my w-col for output
    const int g  = l >> 4;        // quad
    const int v0 = (g & 1) * 8;   // my v-range base (fixed across chunks)
    const int uo = g >> 1;        // u = c*2 + uo
    const float* xr = &xlds[(wave * 16 + r) * 68];

    // v-side x cached in registers as float2 pairs (cells 2t, 2t+1)
    float2v A0v[4], Xv[4], Yv[4], Zv[4];
    {
        float a[8], b[24];
        #pragma unroll
        for (int q = 0; q < 2; q++) *(float4v*)&a[q * 4] = *(const float4v*)(xr + v0 + q * 4);
        #pragma unroll
        for (int q = 0; q < 6; q++) *(float4v*)&b[q * 4] = *(const float4v*)(xr + 16 + v0 * 3 + q * 4);
        #pragma unroll
        for (int t = 0; t < 4; t++) {
            A0v[t] = (float2v){a[2 * t], a[2 * t + 1]};
            Xv[t]  = (float2v){b[6 * t + 0], b[6 * t + 3]};
            Yv[t]  = (float2v){b[6 * t + 1], b[6 * t + 4]};
            Zv[t]  = (float2v){b[6 * t + 2], b[6 * t + 5]};
        }
    }

    float4v acc[13];
    #pragma unroll
    for (int m = 0; m < 13; m++) acc[m] = (float4v){0.f, 0.f, 0.f, 0.f};

    // m-slot -> path: 0:w0  1:w2  2-4:w1  5-7:w3  8-12:w4
    constexpr int pm[13] = {0, 1, 2, 2, 2, 3, 3, 3, 4, 4, 4, 4, 4};

    const short8* wbase = (const short8*)wfrag;

    #pragma unroll
    for (int c = 0; c < 8; c++) {
        // W B-fragments for this chunk (L2-resident, fully coalesced)
        short8 wf[5];
        #pragma unroll
        for (int p = 0; p < 5; p++) wf[p] = wbase[(c * 5 + p) * 64 + l];

        const int u = c * 2 + uo;
        const float u0 = xr[u];
        const float ux = xr[16 + u * 3 + 0];
        const float uy = xr[16 + u * 3 + 1];
        const float uz = xr[16 + u * 3 + 2];

        unsigned fri[13][4];
        #pragma unroll
        for (int t = 0; t < 4; t++) {
            const float2v X = Xv[t], Y = Yv[t], Z = Zv[t];
            const float2v p00 = ux * X, p01 = ux * Y, p02 = ux * Z;
            const float2v p10 = uy * X, p11 = uy * Y, p12 = uy * Z;
            const float2v p20 = uz * X, p21 = uz * Y, p22 = uz * Z;
            float2v bv[13];
            bv[0]  = u0 * A0v[t];                 // 0e x 0e
            bv[1]  = p00 + p11 + p22;             // dot      (1/sqrt3 in epilogue)
            bv[2]  = u0 * X;                      // 0e x 1o
            bv[3]  = u0 * Y;
            bv[4]  = u0 * Z;
            bv[5]  = p12 - p21;                   // cross    (s2 in epilogue)
            bv[6]  = p20 - p02;
            bv[7]  = p01 - p10;
            bv[8]  = p01 + p10;                   // 2e: xy
            bv[9]  = p12 + p21;                   //     yz
            bv[10] = 2.0f * p22 - p00 - p11;      //     3z^2-r^2 (1/sqrt6)
            bv[11] = p02 + p20;                   //     xz
            bv[12] = p00 - p11;                   //     x^2-y^2  (s2)
            #pragma unroll
            for (int m = 0; m < 13; m++) fri[m][t] = pkbf(bv[m].x, bv[m].y);
        }

        #pragma unroll
        for (int m = 0; m < 13; m++) {
            short8 frm = __builtin_bit_cast(short8, *(unsigned __attribute__((ext_vector_type(4)))*)fri[m]);
            acc[m] = __builtin_amdgcn_mfma_f32_16x16x32_bf16(frm, wf[pm[m]], acc[m], 0, 0, 0);
        }
    }

    // ---- Epilogue: scale + store. lane: w = l&15, rows z0 + g*4 + reg ----
    const int w = r;
    float* outp = out + (z0 + g * 4) * 192;
    #pragma unroll
    for (int reg = 0; reg < 4; reg++) {
        float* rowp = outp + reg * 192;
        rowp[w] = S_A * acc[0][reg] + S_B * acc[1][reg];      // 0e (two paths)
        rowp[16 + w * 3 + 0]  = S_C * acc[2][reg];            // 1o
        rowp[16 + w * 3 + 1]  = S_C * acc[3][reg];
        rowp[16 + w * 3 + 2]  = S_C * acc[4][reg];
        rowp[64 + w * 3 + 0]  = S_A * acc[5][reg];            // 1e
        rowp[64 + w * 3 + 1]  = S_A * acc[6][reg];
        rowp[64 + w * 3 + 2]  = S_A * acc[7][reg];
        rowp[112 + w * 5 + 0] = S_A * acc[8][reg];            // 2e
        rowp[112 + w * 5 + 1] = S_A * acc[9][reg];
        rowp[112 + w * 5 + 2] = S_B * acc[10][reg];
        rowp[112 + w * 5 + 3] = S_A * acc[11][reg];
        rowp[112 + w * 5 + 4] = S_A * acc[12][reg];
    }
}

extern "C" void kernel_launch(void* const* d_in, const int* in_sizes, int n_in,
                              void* d_out, int out_size, void* d_ws, size_t ws_size,
                              hipStream_t stream) {
    const float* x  = (const float*)d_in[0];
    const float* w0 = (const float*)d_in[1];
    const float* w1 = (const float*)d_in[2];
    const float* w2 = (const float*)d_in[3];
    const float* w3 = (const float*)d_in[4];
    const float* w4 = (const float*)d_in[5];
    float* out = (float*)d_out;
    unsigned short* wfrag = (unsigned short*)d_ws;   // 40 KB used
    (void)ws_size; (void)n_in; (void)out_size;

    const int nrows = in_sizes[0] / 64;              // 100000
    const int nblocks = (nrows + 63) / 64;           // 1563

    // path order: {w0, w2, w1, w3, w4}
    wprep_kernel<<<dim3(80), dim3(256), 0, stream>>>(w0, w2, w1, w3, w4, wfrag);
    tsq_kernel<<<dim3(nblocks), dim3(256), 0, stream>>>(x, wfrag, out, nrows);
}

// Round 4
// 137.381 us; speedup vs baseline: 1.3849x; 1.0163x over previous
//
#include <hip/hip_runtime.h>
#include <hip/hip_bf16.h>

typedef __attribute__((ext_vector_type(8))) short short8;
typedef __attribute__((ext_vector_type(4))) float float4v;
typedef __attribute__((ext_vector_type(2))) float float2v;
typedef __attribute__((ext_vector_type(4))) unsigned uint4v;

#define S_A 0.04419417382415922f   // 1/(16*sqrt(2)) : a2, and a1*s2
#define S_B 0.025515518153991442f  // 1/(16*sqrt(6)) : a2/sqrt(3), and a1/sqrt(6)
#define S_C 0.0625f                // 1/16 : a1

// Pack two fp32 -> two bf16 (RNE) in one dword: low = a, high = b.
static __device__ __forceinline__ unsigned pkbf(float a, float b) {
#if __has_builtin(__builtin_amdgcn_cvt_pk_bf16_f32)
    auto v = __builtin_amdgcn_cvt_pk_bf16_f32(a, b);   // v_cvt_pk_bf16_f32 (gfx950)
    return __builtin_bit_cast(unsigned, v);
#else
    unsigned ua = __builtin_bit_cast(unsigned, a);
    unsigned ub = __builtin_bit_cast(unsigned, b);
    ua += 0x7fffu + ((ua >> 16) & 1u);                 // RNE
    ub += 0x7fffu + ((ub >> 16) & 1u);
    return __builtin_amdgcn_perm(ub, ua, 0x07060302);  // {hi16(ub), hi16(ua)}
#endif
}

// ---- Prep: W (5 x 16^3 fp32) -> bf16 in MFMA B-fragment layout in d_ws ----
// path ids after reorder: 0=w0, 1=w2, 2=w1, 3=w3, 4=w4
// addr: k=c*32+kk, lane=(kk>>3)*16+w, j=kk&7 -> wout[((c*5+p)*64+lane)*8+j]
__global__ void wprep_kernel(const float* __restrict__ wA, const float* __restrict__ wB,
                             const float* __restrict__ wC, const float* __restrict__ wD,
                             const float* __restrict__ wE, unsigned short* __restrict__ wout)
{
    int e = blockIdx.x * 256 + threadIdx.x;
    if (e >= 5 * 4096) return;
    int p = e >> 12;
    int rem = e & 4095;                    // rem = k*16 + w
    const float* wp = (p == 0) ? wA : (p == 1) ? wB : (p == 2) ? wC : (p == 3) ? wD : wE;
    unsigned u = __builtin_bit_cast(unsigned, wp[rem]);
    u += 0x7fffu + ((u >> 16) & 1u);       // RNE to bf16
    int k = rem >> 4, w = rem & 15;
    int c = k >> 5, kk = k & 31;
    int lane = ((kk >> 3) << 4) | w;
    int j = kk & 7;
    wout[(((c * 5 + p) * 64 + lane) << 3) | j] = (unsigned short)(u >> 16);
}

// Wave-specialized by m-group. Block = 4 waves = ONE 16-row z-tile.
// Groups (disjoint output dwords):
//   G0: m{2,3,4}   (1o)          products: u0*X,Y,Z          path w1
//   G1: m{0,1,10,12} (0e + 2e diag) products: u0*A0, p00,p11,p22  paths w0,w2,w4
//   G2: m{5,6,7}   (1e)          products: 6 off-diag        path w3
//   G3: m{8,9,11}  (2e off-diag) products: 6 off-diag        path w4
// A-frag: lane l holds A[row=l&15][k=c*32+(l>>4)*8+j]; B-frag: W[k][w=l&15]
// C/D: lane l, reg r -> D[row=(l>>4)*4+r][col=l&15]
template<int G>
static __device__ __forceinline__ void run_group(
    const float* __restrict__ xr, int l, const short8* __restrict__ wbase,
    float* __restrict__ out, long long z0)
{
    const int r  = l & 15;
    const int g  = l >> 4;
    const int v0 = (g & 1) * 8;
    const int uo = g >> 1;

    // v-side cache (float2 over cell pairs 2t, 2t+1)
    float2v Xv[4], Yv[4], Zv[4];
    float2v A0v[4];
    {
        float b[24];
        #pragma unroll
        for (int q = 0; q < 6; q++)
            *(float4v*)&b[q * 4] = *(const float4v*)(xr + 16 + v0 * 3 + q * 4);
        #pragma unroll
        for (int t = 0; t < 4; t++) {
            Xv[t] = (float2v){b[6 * t + 0], b[6 * t + 3]};
            Yv[t] = (float2v){b[6 * t + 1], b[6 * t + 4]};
            Zv[t] = (float2v){b[6 * t + 2], b[6 * t + 5]};
        }
        if constexpr (G == 1) {
            float a[8];
            #pragma unroll
            for (int q = 0; q < 2; q++)
                *(float4v*)&a[q * 4] = *(const float4v*)(xr + v0 + q * 4);
            #pragma unroll
            for (int t = 0; t < 4; t++) A0v[t] = (float2v){a[2 * t], a[2 * t + 1]};
        }
    }

    constexpr int NS = (G == 1) ? 4 : 3;
    float4v acc[NS];
    #pragma unroll
    for (int s = 0; s < NS; s++) acc[s] = (float4v){0.f, 0.f, 0.f, 0.f};

    #pragma unroll
    for (int c = 0; c < 8; c++) {
        // B-fragments for this chunk (L2-resident, coalesced dwordx4)
        short8 wfA, wfB, wfC;
        if constexpr (G == 0) wfA = wbase[(c * 5 + 2) * 64 + l];
        if constexpr (G == 1) {
            wfA = wbase[(c * 5 + 0) * 64 + l];
            wfB = wbase[(c * 5 + 1) * 64 + l];
            wfC = wbase[(c * 5 + 4) * 64 + l];
        }
        if constexpr (G == 2) wfA = wbase[(c * 5 + 3) * 64 + l];
        if constexpr (G == 3) wfA = wbase[(c * 5 + 4) * 64 + l];

        const int u = c * 2 + uo;
        float u0 = 0.f, ux = 0.f, uy = 0.f, uz = 0.f;
        if constexpr (G == 0 || G == 1) u0 = xr[u];
        if constexpr (G != 0) {
            ux = xr[16 + u * 3 + 0];
            uy = xr[16 + u * 3 + 1];
            uz = xr[16 + u * 3 + 2];
        }

        unsigned fri[NS][4];
        #pragma unroll
        for (int t = 0; t < 4; t++) {
            const float2v X = Xv[t], Y = Yv[t], Z = Zv[t];
            if constexpr (G == 0) {
                float2v b2 = u0 * X, b3 = u0 * Y, b4 = u0 * Z;
                fri[0][t] = pkbf(b2.x, b2.y);
                fri[1][t] = pkbf(b3.x, b3.y);
                fri[2][t] = pkbf(b4.x, b4.y);
            }
            if constexpr (G == 1) {
                float2v p00 = ux * X, p11 = uy * Y, p22 = uz * Z;
                float2v b0 = u0 * A0v[t];
                float2v b1 = p00 + p11 + p22;
                float2v b10 = 2.0f * p22 - p00 - p11;
                float2v b12 = p00 - p11;
                fri[0][t] = pkbf(b0.x, b0.y);
                fri[1][t] = pkbf(b1.x, b1.y);
                fri[2][t] = pkbf(b10.x, b10.y);
                fri[3][t] = pkbf(b12.x, b12.y);
            }
            if constexpr (G == 2) {
                float2v p01 = ux * Y, p02 = ux * Z, p10 = uy * X;
                float2v p12 = uy * Z, p20 = uz * X, p21 = uz * Y;
                float2v b5 = p12 - p21, b6 = p20 - p02, b7 = p01 - p10;
                fri[0][t] = pkbf(b5.x, b5.y);
                fri[1][t] = pkbf(b6.x, b6.y);
                fri[2][t] = pkbf(b7.x, b7.y);
            }
            if constexpr (G == 3) {
                float2v p01 = ux * Y, p02 = ux * Z, p10 = uy * X;
                float2v p12 = uy * Z, p20 = uz * X, p21 = uz * Y;
                float2v b8 = p01 + p10, b9 = p12 + p21, b11 = p02 + p20;
                fri[0][t] = pkbf(b8.x, b8.y);
                fri[1][t] = pkbf(b9.x, b9.y);
                fri[2][t] = pkbf(b11.x, b11.y);
            }
        }

        #pragma unroll
        for (int s = 0; s < NS; s++) {
            short8 frm = __builtin_bit_cast(short8, *(uint4v*)fri[s]);
            const short8& wf = (G == 1) ? ((s == 0) ? wfA : (s == 1) ? wfB : wfC) : wfA;
            acc[s] = __builtin_amdgcn_mfma_f32_16x16x32_bf16(frm, wf, acc[s], 0, 0, 0);
        }
    }

    // ---- Epilogue: scale + store. w = l&15, rows z0 + g*4 + reg ----
    const int w = r;
    float* outp = out + (z0 + g * 4) * 192;
    #pragma unroll
    for (int reg = 0; reg < 4; reg++) {
        float* rowp = outp + reg * 192;
        if constexpr (G == 0) {
            rowp[16 + w * 3 + 0] = S_C * acc[0][reg];
            rowp[16 + w * 3 + 1] = S_C * acc[1][reg];
            rowp[16 + w * 3 + 2] = S_C * acc[2][reg];
        }
        if constexpr (G == 1) {
            rowp[w]               = S_A * acc[0][reg] + S_B * acc[1][reg];
            rowp[112 + w * 5 + 2] = S_B * acc[2][reg];
            rowp[112 + w * 5 + 4] = S_A * acc[3][reg];
        }
        if constexpr (G == 2) {
            rowp[64 + w * 3 + 0] = S_A * acc[0][reg];
            rowp[64 + w * 3 + 1] = S_A * acc[1][reg];
            rowp[64 + w * 3 + 2] = S_A * acc[2][reg];
        }
        if constexpr (G == 3) {
            rowp[112 + w * 5 + 0] = S_A * acc[0][reg];
            rowp[112 + w * 5 + 1] = S_A * acc[1][reg];
            rowp[112 + w * 5 + 3] = S_A * acc[2][reg];
        }
    }
}

__global__ __launch_bounds__(256)
void tsq_kernel(const float* __restrict__ x,
                const unsigned short* __restrict__ wfrag,
                float* __restrict__ out,
                int nrows)
{
    // one 16-row z-tile per block; stride 68 keeps LDS aliasing at free 2-way
    __shared__ __attribute__((aligned(16))) float xlds[16 * 68];

    const int tid = threadIdx.x;
    const long long z0 = (long long)blockIdx.x * 16;

    // stage 16 rows x 64 floats, one float4 per thread, fully coalesced
    {
        const float* xg = x + z0 * 64;
        int f = tid * 4;
        int row = f >> 6, col = f & 63;
        float4v v = {0.f, 0.f, 0.f, 0.f};
        if (z0 + row < nrows) v = *(const float4v*)(xg + f);
        *(float4v*)&xlds[row * 68 + col] = v;
    }
    __syncthreads();
    if (z0 >= nrows) return;

    const int wave = tid >> 6;
    const int l = tid & 63;
    const float* xr = &xlds[(l & 15) * 68];
    const short8* wbase = (const short8*)wfrag;

    if      (wave == 0) run_group<0>(xr, l, wbase, out, z0);
    else if (wave == 1) run_group<1>(xr, l, wbase, out, z0);
    else if (wave == 2) run_group<2>(xr, l, wbase, out, z0);
    else                run_group<3>(xr, l, wbase, out, z0);
}

extern "C" void kernel_launch(void* const* d_in, const int* in_sizes, int n_in,
                              void* d_out, int out_size, void* d_ws, size_t ws_size,
                              hipStream_t stream) {
    const float* x  = (const float*)d_in[0];
    const float* w0 = (const float*)d_in[1];
    const float* w1 = (const float*)d_in[2];
    const float* w2 = (const float*)d_in[3];
    const float* w3 = (const float*)d_in[4];
    const float* w4 = (const float*)d_in[5];
    float* out = (float*)d_out;
    unsigned short* wfrag = (unsigned short*)d_ws;   // 40 KB used
    (void)ws_size; (void)n_in; (void)out_size;

    const int nrows = in_sizes[0] / 64;              // 100000
    const int nblocks = (nrows + 15) / 16;           // 6250

    // path order: {w0, w2, w1, w3, w4}
    wprep_kernel<<<dim3(80), dim3(256), 0, stream>>>(w0, w2, w1, w3, w4, wfrag);
    tsq_kernel<<<dim3(nblocks), dim3(256), 0, stream>>>(x, wfrag, out, nrows);
}